// Round 1
// baseline (2974.132 us; speedup 1.0000x reference)
//
#include <hip/hip_runtime.h>
#include <math.h>

#define NNODES 50000
#define NEDGES 600000
#define DIM 128
#define GNSZ 5000
#define GESZ 60000
#define NDTOT (NNODES*DIM)
#define EPS_NORM 1e-5f
#define EPS_RED  1e-6f

union F4 { float4 v; float f[4]; };

__device__ __forceinline__ float4 ld4(const float* p){ return *(const float4*)p; }

// ---------------------------------------------------------------------------
// K1: node GEMMs.  Ah -> out_h (temporary), Bh/Dh/Eh -> ws.
// Block: 32 nodes x 128 outs, thread tile 4x4 (8 trow x 32 tcol).
// A tile in LDS (padded 129 to break bank conflicts), B (W) via float4 from L2.
// ---------------------------------------------------------------------------
__global__ __launch_bounds__(256) void k1_node_gemm(
    const float* __restrict__ h, const float* __restrict__ W, const float* __restrict__ bias,
    float* __restrict__ Ah, float* __restrict__ Bh, float* __restrict__ Dh, float* __restrict__ Eh)
{
  __shared__ float as[32][129];
  const int t = threadIdx.x;
  const int base = blockIdx.x * 32;
  #pragma unroll
  for (int i = 0; i < 4; i++){
    int f = t + i*256;
    int row = f >> 5, c4 = (f & 31) * 4;
    float4 v = make_float4(0.f,0.f,0.f,0.f);
    if (base + row < NNODES) v = ld4(h + (size_t)(base+row)*DIM + c4);
    as[row][c4+0]=v.x; as[row][c4+1]=v.y; as[row][c4+2]=v.z; as[row][c4+3]=v.w;
  }
  __syncthreads();
  const int tcol = t & 31, trow = t >> 5;
  float* outp[4] = {Ah, Bh, Dh, Eh};
  const int mats[4] = {0,1,3,4};
  #pragma unroll 1
  for (int mi = 0; mi < 4; mi++){
    const float* Wm = W + mats[mi]*(DIM*DIM);
    float acc[4][4];
    #pragma unroll
    for (int i=0;i<4;i++){
      #pragma unroll
      for (int j=0;j<4;j++) acc[i][j]=0.f;
    }
    #pragma unroll 4
    for (int k = 0; k < DIM; k++){
      F4 bv; bv.v = ld4(Wm + k*DIM + tcol*4);
      float a0 = as[trow*4+0][k], a1 = as[trow*4+1][k];
      float a2 = as[trow*4+2][k], a3 = as[trow*4+3][k];
      #pragma unroll
      for (int j=0;j<4;j++){
        acc[0][j] += a0*bv.f[j]; acc[1][j] += a1*bv.f[j];
        acc[2][j] += a2*bv.f[j]; acc[3][j] += a3*bv.f[j];
      }
    }
    F4 bb; bb.v = ld4(bias + mats[mi]*DIM + tcol*4);
    #pragma unroll
    for (int i=0;i<4;i++){
      int row = base + trow*4 + i;
      if (row < NNODES){
        F4 o;
        #pragma unroll
        for (int j=0;j<4;j++) o.f[j] = acc[i][j] + bb.f[j];
        *(float4*)(outp[mi] + (size_t)row*DIM + tcol*4) = o.v;
      }
    }
  }
}

// ---------------------------------------------------------------------------
// K2: fused edge pipeline.  Ce GEMM + gather Dh[src]+Eh[dst] -> e_new (d_out),
// sigmoid, atomic num/den accumulation, per-graph e-stats (sum, sumsq).
// 32 edges/block (divides 60000 -> block never straddles a graph).
// ---------------------------------------------------------------------------
__global__ __launch_bounds__(256) void k2_edge(
    const float* __restrict__ e, const int* __restrict__ src, const int* __restrict__ dst,
    const float* __restrict__ W, const float* __restrict__ bias,
    const float* __restrict__ Bh, const float* __restrict__ Dh, const float* __restrict__ Eh,
    const float* __restrict__ snorm_e,
    float* __restrict__ e_new, float* __restrict__ num, float* __restrict__ den,
    float* __restrict__ sum_e, float* __restrict__ sumsq_e)
{
  __shared__ float as[32][129];
  __shared__ int ssrc[32], sdst[32];
  __shared__ float s_sum[128], s_sq[128];
  const int t = threadIdx.x;
  const int base = blockIdx.x * 32;
  if (t < 128){ s_sum[t]=0.f; s_sq[t]=0.f; }
  if (t >= 128 && t < 160) ssrc[t-128] = src[base + t - 128];
  if (t >= 160 && t < 192) sdst[t-160] = dst[base + t - 160];
  #pragma unroll
  for (int i = 0; i < 4; i++){
    int f = t + i*256;
    int row = f >> 5, c4 = (f & 31)*4;
    float4 v = ld4(e + (size_t)(base+row)*DIM + c4);
    as[row][c4+0]=v.x; as[row][c4+1]=v.y; as[row][c4+2]=v.z; as[row][c4+3]=v.w;
  }
  __syncthreads();
  const int tcol = t & 31, trow = t >> 5;
  const float* W2 = W + 2*(DIM*DIM);
  float acc[4][4];
  #pragma unroll
  for (int i=0;i<4;i++){
    #pragma unroll
    for (int j=0;j<4;j++) acc[i][j]=0.f;
  }
  #pragma unroll 4
  for (int k = 0; k < DIM; k++){
    F4 bv; bv.v = ld4(W2 + k*DIM + tcol*4);
    float a0 = as[trow*4+0][k], a1 = as[trow*4+1][k];
    float a2 = as[trow*4+2][k], a3 = as[trow*4+3][k];
    #pragma unroll
    for (int j=0;j<4;j++){
      acc[0][j] += a0*bv.f[j]; acc[1][j] += a1*bv.f[j];
      acc[2][j] += a2*bv.f[j]; acc[3][j] += a3*bv.f[j];
    }
  }
  F4 b2; b2.v = ld4(bias + 2*DIM + tcol*4);
  const float sn = snorm_e[0];
  float lsum[4] = {0,0,0,0}, lsq[4] = {0,0,0,0};
  #pragma unroll
  for (int i=0;i<4;i++){
    int el = trow*4 + i;
    int sgl = ssrc[el], dgl = sdst[el];
    F4 dh;  dh.v  = ld4(Dh + (size_t)sgl*DIM + tcol*4);
    F4 ehv; ehv.v = ld4(Eh + (size_t)dgl*DIM + tcol*4);
    F4 bh;  bh.v  = ld4(Bh + (size_t)sgl*DIM + tcol*4);
    F4 o;
    #pragma unroll
    for (int j=0;j<4;j++) o.f[j] = acc[i][j] + b2.f[j] + dh.f[j] + ehv.f[j];
    *(float4*)(e_new + (size_t)(base+el)*DIM + tcol*4) = o.v;
    #pragma unroll
    for (int j=0;j<4;j++){
      float sig = 1.f/(1.f + __expf(-o.f[j]));
      atomicAdd(&num[(size_t)dgl*DIM + tcol*4 + j], sig * bh.f[j]);
      atomicAdd(&den[(size_t)dgl*DIM + tcol*4 + j], sig);
      float x = o.f[j]*sn;
      lsum[j] += x; lsq[j] += x*x;
    }
  }
  #pragma unroll
  for (int j=0;j<4;j++){
    atomicAdd(&s_sum[tcol*4+j], lsum[j]);
    atomicAdd(&s_sq[tcol*4+j],  lsq[j]);
  }
  __syncthreads();
  if (t < 128){
    int g = base / GESZ;
    atomicAdd(&sum_e[g*DIM + t],  s_sum[t]);
    atomicAdd(&sumsq_e[g*DIM + t], s_sq[t]);
  }
}

// ---------------------------------------------------------------------------
// K3: h_pre = where(den>0, Ah + num/(den+eps), h) * snorm_n  (in place in
// out_h, which currently holds Ah), plus per-graph h-stats.
// 8 nodes/block (divides 5000).
// ---------------------------------------------------------------------------
__global__ __launch_bounds__(256) void k3_node_update(
    const float* __restrict__ h,
    const float* __restrict__ num, const float* __restrict__ den,
    const float* __restrict__ snorm_n,
    float* hbuf,                     // in: Ah, out: h_pre (same memory)
    float* __restrict__ sum_h, float* __restrict__ sumsq_h)
{
  __shared__ float s_sum[128], s_sq[128];
  const int t = threadIdx.x;
  if (t < 128){ s_sum[t]=0.f; s_sq[t]=0.f; }
  __syncthreads();
  int idx4 = blockIdx.x*256 + t;
  int node = idx4 >> 5;
  int c4 = (idx4 & 31) * 4;
  size_t off = (size_t)node*DIM + c4;
  F4 a, nm, dn, hh;
  a.v = *(float4*)(hbuf + off);
  nm.v = ld4(num+off); dn.v = ld4(den+off); hh.v = ld4(h+off);
  const float sn = snorm_n[0];
  F4 x;
  #pragma unroll
  for (int j=0;j<4;j++){
    float d = dn.f[j];
    float v = (d > 0.f) ? (a.f[j] + nm.f[j]/(d + EPS_RED)) : hh.f[j];
    x.f[j] = v * sn;
  }
  *(float4*)(hbuf + off) = x.v;
  #pragma unroll
  for (int j=0;j<4;j++){
    atomicAdd(&s_sum[c4+j], x.f[j]);
    atomicAdd(&s_sq[c4+j],  x.f[j]*x.f[j]);
  }
  __syncthreads();
  if (t < 128){
    int g = (blockIdx.x*8) / GNSZ;
    atomicAdd(&sum_h[g*DIM+t],   s_sum[t]);
    atomicAdd(&sumsq_h[g*DIM+t], s_sq[t]);
  }
}

// ---------------------------------------------------------------------------
// K4: finalize mean / 1/(std+eps) for e and h stats.
// stats layout (floats): sum_e[0], sumsq_e[1280], sum_h[2560], sumsq_h[3840],
//                        mean_e[5120], inv_e[6400], mean_h[7680], inv_h[8960]
// ---------------------------------------------------------------------------
__global__ void k4_finalize(float* __restrict__ stats)
{
  int idx = blockIdx.x*256 + threadIdx.x;
  if (idx >= 2560) return;
  int which = idx / 1280;            // 0 = e, 1 = h
  int i = idx - which*1280;
  float n = which ? (float)GNSZ : (float)GESZ;
  float s  = stats[which*2560 + i];
  float sq = stats[which*2560 + 1280 + i];
  float mean = s / n;
  float var = (sq - s*s/n) / (n - 1.f);
  var = fmaxf(var, 0.f);
  float inv = 1.f / (sqrtf(var) + EPS_NORM);
  stats[5120 + which*2560 + i] = mean;
  stats[5120 + which*2560 + 1280 + i] = inv;
}

// ---------------------------------------------------------------------------
// K5h: out_h = h_in + relu(gamma*(h_pre - mean)*inv + beta), in place.
// ---------------------------------------------------------------------------
__global__ __launch_bounds__(256) void k5_norm_h(
    const float* __restrict__ h_in, const float* __restrict__ gamma, const float* __restrict__ beta,
    const float* __restrict__ stats, float* outp)
{
  int idx4 = blockIdx.x*256 + threadIdx.x;
  int node = idx4 >> 5;
  int c4 = (idx4 & 31)*4;
  int g = node / GNSZ;
  size_t off = (size_t)node*DIM + c4;
  F4 x;  x.v  = *(float4*)(outp + off);
  F4 mn; mn.v = ld4(stats + 7680 + g*DIM + c4);
  F4 iv; iv.v = ld4(stats + 8960 + g*DIM + c4);
  F4 gm; gm.v = ld4(gamma + c4);
  F4 bt; bt.v = ld4(beta + c4);
  F4 hi; hi.v = ld4(h_in + off);
  F4 o;
  #pragma unroll
  for (int j=0;j<4;j++){
    float y = gm.f[j]*((x.f[j]-mn.f[j])*iv.f[j]) + bt.f[j];
    o.f[j] = hi.f[j] + fmaxf(y, 0.f);
  }
  *(float4*)(outp + off) = o.v;
}

// ---------------------------------------------------------------------------
// K5e: out_e = e_in + relu(gamma*((e_new*sn - mean)*inv) + beta), in place.
// ---------------------------------------------------------------------------
__global__ __launch_bounds__(256) void k5_norm_e(
    const float* __restrict__ e_in, const float* __restrict__ gamma, const float* __restrict__ beta,
    const float* __restrict__ snorm_e, const float* __restrict__ stats, float* outp)
{
  int idx4 = blockIdx.x*256 + threadIdx.x;
  int edge = idx4 >> 5;
  int c4 = (idx4 & 31)*4;
  int g = edge / GESZ;
  size_t off = (size_t)edge*DIM + c4;
  const float sn = snorm_e[0];
  F4 x;  x.v  = *(float4*)(outp + off);
  F4 mn; mn.v = ld4(stats + 5120 + g*DIM + c4);
  F4 iv; iv.v = ld4(stats + 6400 + g*DIM + c4);
  F4 gm; gm.v = ld4(gamma + c4);
  F4 bt; bt.v = ld4(beta + c4);
  F4 ei; ei.v = ld4(e_in + off);
  F4 o;
  #pragma unroll
  for (int j=0;j<4;j++){
    float xx = x.f[j]*sn;
    float y = gm.f[j]*((xx-mn.f[j])*iv.f[j]) + bt.f[j];
    o.f[j] = ei.f[j] + fmaxf(y, 0.f);
  }
  *(float4*)(outp + off) = o.v;
}

extern "C" void kernel_launch(void* const* d_in, const int* in_sizes, int n_in,
                              void* d_out, int out_size, void* d_ws, size_t ws_size,
                              hipStream_t stream)
{
  (void)in_sizes; (void)n_in; (void)out_size; (void)ws_size;
  const float* h    = (const float*)d_in[0];
  const float* e    = (const float*)d_in[1];
  const int*   src  = (const int*)d_in[2];
  const int*   dst  = (const int*)d_in[3];
  const float* snorm_n = (const float*)d_in[4];
  const float* snorm_e = (const float*)d_in[5];
  const float* W    = (const float*)d_in[6];
  const float* bias = (const float*)d_in[7];
  const float* gamma_h = (const float*)d_in[8];
  const float* beta_h  = (const float*)d_in[9];
  const float* gamma_e = (const float*)d_in[10];
  const float* beta_e  = (const float*)d_in[11];

  float* out_h = (float*)d_out;                 // holds Ah, then h_pre, then h_new
  float* out_e = out_h + (size_t)NDTOT;         // holds e_new, then e_out
  float* ws  = (float*)d_ws;
  float* Bh  = ws;
  float* Dh  = ws + 1*(size_t)NDTOT;
  float* Eh  = ws + 2*(size_t)NDTOT;
  float* num = ws + 3*(size_t)NDTOT;
  float* den = ws + 4*(size_t)NDTOT;
  float* stats = ws + 5*(size_t)NDTOT;          // 10240 floats

  // zero num, den, and sum/sumsq stats (ws is poisoned before every launch)
  hipMemsetAsync(num, 0, (2*(size_t)NDTOT + 5120)*sizeof(float), stream);

  k1_node_gemm<<<1563, 256, 0, stream>>>(h, W, bias, out_h, Bh, Dh, Eh);
  k2_edge<<<18750, 256, 0, stream>>>(e, src, dst, W, bias, Bh, Dh, Eh, snorm_e,
                                     out_e, num, den, stats, stats+1280);
  k3_node_update<<<6250, 256, 0, stream>>>(h, num, den, snorm_n, out_h,
                                           stats+2560, stats+3840);
  k4_finalize<<<10, 256, 0, stream>>>(stats);
  k5_norm_h<<<6250, 256, 0, stream>>>(h, gamma_h, beta_h, stats, out_h);
  k5_norm_e<<<75000, 256, 0, stream>>>(e, gamma_e, beta_e, snorm_e, stats, out_e);
}